// Round 9
// baseline (44379.263 us; speedup 1.0000x reference)
//
#include <hip/hip_runtime.h>
#include <hip/hip_cooperative_groups.h>

namespace cg = cooperative_groups;

// LSTMGapFiller R10: persistent cooperative decoder + R9's async LDS weight
// staging. R4's persistent failure was the 30MB/step refetch at 230 GB/s
// latency-bound (counters: MfmaUtil 5%, hbm 152-274 GB/s) - NOT the sync
// protocol. R9 proved global_load_lds fixes that stream. Compose both:
// per step = phase A (gen l0, staged weights, block-local logits/argmax of
// t-1 from h1) | grid.sync | phase B (gen l1, staged) | grid.sync.
// c-state in registers (kills cst global round-trip; R4 FETCH was 30MB/step
// vs 12MB weights). Next-phase staging issued BEFORE each sync (read-only,
// survives it; LDS parity: A ends bsm[1], B starts bsm[0]). 512 launches gone.
// Context stack unchanged (R3).

#define L_SEQ 100
#define BATCH 1024
#define HCTX 256
#define HG 512
#define TDEC 256

typedef __attribute__((ext_vector_type(8))) short bf16x8;
typedef __attribute__((ext_vector_type(4))) float f32x4;

__device__ __forceinline__ float sigf(float x){ return 1.0f/(1.0f+expf(-x)); }
__device__ __forceinline__ unsigned short f2bf(float x){
  unsigned int u = __float_as_uint(x);
  return (unsigned short)((u + 0x7fffu + ((u>>16)&1u)) >> 16);   // RNE
}
__device__ __forceinline__ float bf2f(unsigned short h){
  return __uint_as_float(((unsigned int)h)<<16);
}

// Pack W[G][K] (fp32, row-major) into MFMA-fragment-linear bf16 hi/lo.
__global__ void pack_w(const float* __restrict__ W, int G, int K, int KTtot, int kt0,
                       unsigned short* __restrict__ hi, unsigned short* __restrict__ lo){
  int idx = blockIdx.x*blockDim.x + threadIdx.x;
  int kt_n = K/32;
  int total = (G/16)*kt_n*64;
  if (idx >= total) return;
  int lane = idx & 63;
  int ktl = (idx>>6) % kt_n;
  int gt  = (idx>>6) / kt_n;
  int g = gt*16 + (lane & 15);
  int k = ktl*32 + (lane>>4)*8;
  const float* src = W + (size_t)g*K + k;
  size_t dst = (((size_t)gt*KTtot + (kt0 + ktl))*64 + lane)*8;
  #pragma unroll
  for (int j=0;j<8;j++){
    float x = src[j];
    unsigned short h = f2bf(x);
    hi[dst+j] = h;
    lo[dst+j] = f2bf(x - bf2f(h));
  }
}

// embedding projections (vocab=5)
__global__ void embprep(const float* __restrict__ emb,
                        const float* __restrict__ c0Wih, const float* __restrict__ c0b,
                        const float* __restrict__ g0Wih, const float* __restrict__ g0b,
                        float* __restrict__ ectx0, float* __restrict__ egen0){
  int idx = blockIdx.x*blockDim.x + threadIdx.x;
  if (idx < 2*5*1024){
    int d = idx / 5120;
    int v = (idx / 1024) % 5;
    int j = idx % 1024;
    const float* w = c0Wih + ((size_t)d*1024 + j)*64;
    const float* e = emb + v*64;
    float s = c0b[d*1024 + j];
    #pragma unroll
    for (int k=0;k<64;k++) s += e[k]*w[k];
    ectx0[idx] = s;
  } else if (idx < 2*5*1024 + 5*2048){
    int i2 = idx - 10240;
    int v = i2 / 2048;
    int j = i2 % 2048;
    const float* w = g0Wih + (size_t)j*64;
    const float* e = emb + v*64;
    float s = g0b[j];
    #pragma unroll
    for (int k=0;k<64;k++) s += e[k]*w[k];
    egen0[i2] = s;
  }
}

// ---------------- context layer 0 (MFMA) ---------------- (unchanged R3)
__global__ void __launch_bounds__(512,1) ctx_l0_mfma(
    const int* __restrict__ toks,
    const float* __restrict__ ectx0,
    const unsigned short* __restrict__ wh, const unsigned short* __restrict__ wl,
    unsigned short* __restrict__ y0h, unsigned short* __restrict__ y0l)
{
  const int id  = blockIdx.x;
  const int dir = (id >> 2) & 1;
  const int bx  = ((id >> 3) << 2) | (id & 3);
  const int e0  = bx * 16;
  const int lane = threadIdx.x & 63;
  const int w    = threadIdx.x >> 6;
  const int lo16 = lane & 15, kgrp = lane >> 4;

  __shared__ unsigned short hsh[16*256];
  __shared__ unsigned short hsl[16*256];
  __shared__ float cs[16*256];
  for (int i=threadIdx.x;i<16*256;i+=512){ hsh[i]=0; hsl[i]=0; cs[i]=0.f; }
  __syncthreads();

  const unsigned short* pbh[4][2];
  const unsigned short* pbl[4][2];
  #pragma unroll
  for (int g=0;g<4;g++){
    #pragma unroll
    for (int st=0;st<2;st++){
      int ct = g*16 + w*2 + st;
      size_t off = (size_t)dir*1024*256 + ((size_t)(ct*8)*64 + lane)*8;
      pbh[g][st] = wh + off; pbl[g][st] = wl + off;
    }
  }
  const unsigned aoff0 = (unsigned)(lo16*512 + kgrp*16);
  const unsigned axor  = ((unsigned)(lo16 & 7)) << 4;

  for (int s=0;s<L_SEQ;s++){
    const int t = dir ? (L_SEQ-1-s) : s;
    f32x4 zero = {0.f,0.f,0.f,0.f};
    f32x4 acc[4][2];
    #pragma unroll
    for (int g=0;g<4;g++){
      #pragma unroll
      for (int st=0;st<2;st++) acc[g][st] = zero;
    }
    #pragma unroll 2
    for (int kt=0;kt<8;kt++){
      unsigned ao = (aoff0 + kt*64) ^ axor;
      bf16x8 ah = *(const bf16x8*)((const char*)hsh + ao);
      bf16x8 al = *(const bf16x8*)((const char*)hsl + ao);
      #pragma unroll
      for (int g=0;g<4;g++){
        #pragma unroll
        for (int st=0;st<2;st++){
          bf16x8 bh = *(const bf16x8*)(pbh[g][st] + (size_t)kt*512);
          bf16x8 bl = *(const bf16x8*)(pbl[g][st] + (size_t)kt*512);
          acc[g][st] = __builtin_amdgcn_mfma_f32_16x16x32_bf16(ah,bh,acc[g][st],0,0,0);
          acc[g][st] = __builtin_amdgcn_mfma_f32_16x16x32_bf16(al,bh,acc[g][st],0,0,0);
          acc[g][st] = __builtin_amdgcn_mfma_f32_16x16x32_bf16(ah,bl,acc[g][st],0,0,0);
        }
      }
    }
    __syncthreads();
    int tkr[4];
    #pragma unroll
    for (int r=0;r<4;r++) tkr[r] = toks[(e0 + kgrp*4 + r)*L_SEQ + t];
    #pragma unroll
    for (int st=0;st<2;st++){
      const int unit = w*32 + st*16 + lo16;
      #pragma unroll
      for (int r=0;r<4;r++){
        const int row = kgrp*4 + r;
        const int e = e0 + row;
        const float* ep = ectx0 + ((size_t)(dir*5 + tkr[r]))*1024 + unit;
        float zi = acc[0][st][r] + ep[0];
        float zf = acc[1][st][r] + ep[256];
        float zg = acc[2][st][r] + ep[512];
        float zo = acc[3][st][r] + ep[768];
        int ci = row*256 + unit;
        float c = sigf(zf)*cs[ci] + sigf(zi)*tanhf(zg);
        float h = sigf(zo)*tanhf(c);
        cs[ci] = c;
        unsigned short hb = f2bf(h), lb = f2bf(h - bf2f(hb));
        unsigned hoff = ((unsigned)(row*512 + unit*2)) ^ (((unsigned)(row & 7)) << 4);
        *(unsigned short*)((char*)hsh + hoff) = hb;
        *(unsigned short*)((char*)hsl + hoff) = lb;
        size_t yo = ((size_t)t*BATCH + e)*512 + dir*256 + unit;
        y0h[yo] = hb; y0l[yo] = lb;
      }
    }
    __syncthreads();
  }
}

// ---------------- context layer 1 (MFMA) ---------------- (unchanged R3)
__global__ void __launch_bounds__(512,1) ctx_l1_mfma(
    const unsigned short* __restrict__ y0h, const unsigned short* __restrict__ y0l,
    const unsigned short* __restrict__ wh, const unsigned short* __restrict__ wl,
    const float* __restrict__ bias,
    float* __restrict__ finals, int t_store)
{
  const int id  = blockIdx.x;
  const int dir = (id >> 2) & 1;
  const int bx  = ((id >> 3) << 2) | (id & 3);
  const int e0  = bx * 16;
  const int lane = threadIdx.x & 63;
  const int w    = threadIdx.x >> 6;
  const int lo16 = lane & 15, kgrp = lane >> 4;

  __shared__ unsigned short xsh[16*512];
  __shared__ unsigned short xsl[16*512];
  __shared__ unsigned short hsh[16*256];
  __shared__ unsigned short hsl[16*256];
  __shared__ float cs[16*256];
  for (int i=threadIdx.x;i<16*256;i+=512){ hsh[i]=0; hsl[i]=0; cs[i]=0.f; }

  float bb[4][2];
  #pragma unroll
  for (int g=0;g<4;g++){
    #pragma unroll
    for (int st=0;st<2;st++)
      bb[g][st] = bias[dir*1024 + g*256 + w*32 + st*16 + lo16];
  }
  const unsigned short* pbh[4][2];
  const unsigned short* pbl[4][2];
  #pragma unroll
  for (int g=0;g<4;g++){
    #pragma unroll
    for (int st=0;st<2;st++){
      int ct = g*16 + w*2 + st;
      size_t off = (size_t)dir*1024*768 + ((size_t)(ct*24)*64 + lane)*8;
      pbh[g][st] = wh + off; pbl[g][st] = wl + off;
    }
  }
  const unsigned axor = ((unsigned)(lo16 & 7)) << 4;
  __syncthreads();

  for (int s=0;s<L_SEQ;s++){
    const int t = dir ? (L_SEQ-1-s) : s;
    #pragma unroll
    for (int cc=0; cc<2; cc++){
      int ci = threadIdx.x + cc*512;
      int row = ci >> 6, cr = ci & 63;
      const unsigned short* srcbase = y0h + ((size_t)t*BATCH + e0 + row)*512 + cr*8;
      const unsigned short* srcbasel = y0l + ((size_t)t*BATCH + e0 + row)*512 + cr*8;
      uint4 vh = *(const uint4*)srcbase;
      uint4 vl = *(const uint4*)srcbasel;
      unsigned xo = ((unsigned)(row*1024 + cr*16)) ^ (((unsigned)(row & 7)) << 4);
      *(uint4*)((char*)xsh + xo) = vh;
      *(uint4*)((char*)xsl + xo) = vl;
    }
    __syncthreads();
    f32x4 zero = {0.f,0.f,0.f,0.f};
    f32x4 acc[4][2];
    #pragma unroll
    for (int g=0;g<4;g++){
      #pragma unroll
      for (int st=0;st<2;st++) acc[g][st] = zero;
    }
    #pragma unroll 2
    for (int kt=0;kt<16;kt++){
      unsigned ao = ((unsigned)(lo16*1024 + kt*64 + kgrp*16)) ^ axor;
      bf16x8 ah = *(const bf16x8*)((const char*)xsh + ao);
      bf16x8 al = *(const bf16x8*)((const char*)xsl + ao);
      #pragma unroll
      for (int g=0;g<4;g++){
        #pragma unroll
        for (int st=0;st<2;st++){
          bf16x8 bh = *(const bf16x8*)(pbh[g][st] + (size_t)kt*512);
          bf16x8 bl = *(const bf16x8*)(pbl[g][st] + (size_t)kt*512);
          acc[g][st] = __builtin_amdgcn_mfma_f32_16x16x32_bf16(ah,bh,acc[g][st],0,0,0);
          acc[g][st] = __builtin_amdgcn_mfma_f32_16x16x32_bf16(al,bh,acc[g][st],0,0,0);
          acc[g][st] = __builtin_amdgcn_mfma_f32_16x16x32_bf16(ah,bl,acc[g][st],0,0,0);
        }
      }
    }
    #pragma unroll 2
    for (int kt=16;kt<24;kt++){
      unsigned ao = ((unsigned)(lo16*512 + (kt-16)*64 + kgrp*16)) ^ axor;
      bf16x8 ah = *(const bf16x8*)((const char*)hsh + ao);
      bf16x8 al = *(const bf16x8*)((const char*)hsl + ao);
      #pragma unroll
      for (int g=0;g<4;g++){
        #pragma unroll
        for (int st=0;st<2;st++){
          bf16x8 bh = *(const bf16x8*)(pbh[g][st] + (size_t)kt*512);
          bf16x8 bl = *(const bf16x8*)(pbl[g][st] + (size_t)kt*512);
          acc[g][st] = __builtin_amdgcn_mfma_f32_16x16x32_bf16(ah,bh,acc[g][st],0,0,0);
          acc[g][st] = __builtin_amdgcn_mfma_f32_16x16x32_bf16(al,bh,acc[g][st],0,0,0);
          acc[g][st] = __builtin_amdgcn_mfma_f32_16x16x32_bf16(ah,bl,acc[g][st],0,0,0);
        }
      }
    }
    __syncthreads();
    #pragma unroll
    for (int st=0;st<2;st++){
      const int unit = w*32 + st*16 + lo16;
      #pragma unroll
      for (int r=0;r<4;r++){
        const int row = kgrp*4 + r;
        float zi = acc[0][st][r] + bb[0][st];
        float zf = acc[1][st][r] + bb[1][st];
        float zg = acc[2][st][r] + bb[2][st];
        float zo = acc[3][st][r] + bb[3][st];
        int ci = row*256 + unit;
        float c = sigf(zf)*cs[ci] + sigf(zi)*tanhf(zg);
        float h = sigf(zo)*tanhf(c);
        cs[ci] = c;
        unsigned short hb = f2bf(h), lb = f2bf(h - bf2f(hb));
        unsigned hoff = ((unsigned)(row*512 + unit*2)) ^ (((unsigned)(row & 7)) << 4);
        *(unsigned short*)((char*)hsh + hoff) = hb;
        *(unsigned short*)((char*)hsl + hoff) = lb;
        if (t == t_store)
          finals[(size_t)(e0 + row)*512 + dir*256 + unit] = h;
      }
    }
    __syncthreads();
  }
}

__global__ void combine_init2(const float* __restrict__ lf, const float* __restrict__ rf,
                              unsigned short* __restrict__ h0h, unsigned short* __restrict__ h0l,
                              unsigned short* __restrict__ h1h, unsigned short* __restrict__ h1l){
  int i = blockIdx.x*blockDim.x + threadIdx.x;
  if (i < BATCH*HG){
    float v = 0.5f*(lf[i]+rf[i]);
    unsigned short h = f2bf(v);
    unsigned short l = f2bf(v - bf2f(h));
    h0h[i]=h; h0l[i]=l; h1h[i]=h; h1l[i]=l;
  }
}

// ---------------- persistent decoder (cooperative + staged weights) ---------
// 256 blocks x 512 thr, 1 block/CU. Per step:
//   A: staged l0 MFMA; block-local logits/argmax of t-1 from h1; epilogue
//   grid.sync
//   B: staged l1 MFMA; epilogue
//   grid.sync
// c-state in registers. Next-phase chunk staged before each sync.
__global__ void __launch_bounds__(512,1) dec_persist(
    const float* __restrict__ egen0,
    const unsigned short* __restrict__ w0h, const unsigned short* __restrict__ w0l,
    const unsigned short* __restrict__ w1h, const unsigned short* __restrict__ w1l,
    const float* __restrict__ bias1,
    const float* __restrict__ outW, const float* __restrict__ outb,
    unsigned short* __restrict__ h0ha, unsigned short* __restrict__ h0la,
    unsigned short* __restrict__ h0hb, unsigned short* __restrict__ h0lb,
    unsigned short* __restrict__ h1ha, unsigned short* __restrict__ h1la,
    unsigned short* __restrict__ h1hb, unsigned short* __restrict__ h1lb,
    float* __restrict__ out)
{
  cg::grid_group grid = cg::this_grid();
  __shared__ unsigned short bsm[2][32768];    // 2 x 64 KB chunks
  const int bid = blockIdx.x;
  const int by = bid & 15;
  const int bx = bid >> 4;
  const int e0 = bx * 64;
  const int lane = threadIdx.x & 63;
  const int w = threadIdx.x >> 6;
  const int wm = w & 3, wu = w >> 2;
  const int ut = by*2 + wu;
  const int lo16 = lane & 15, kgrp = lane >> 4;
  const int arow = e0 + wm*16 + lo16;
  const int u = ut*16 + lo16;
  const int r0 = e0 + wm*16 + kgrp*4;

  const float b10 = bias1[u], b11 = bias1[512+u];
  const float b12 = bias1[1024+u], b13 = bias1[1536+u];

  auto STAGE0 = [&](int c){
    #pragma unroll
    for (int i=0;i<8;i++){
      int id = w*8 + i;
      int hl  = id & 1;
      int q   = (id >> 1) & 3;
      int wu2 = (id >> 3) & 1;
      int ksl = id >> 4;
      int ks  = c*4 + ksl;
      const unsigned short* src = (hl ? w0l : w0h)
          + (((size_t)(q*32 + by*2 + wu2)*16 + ks)*64 + lane)*8;
      __builtin_amdgcn_global_load_lds((const void*)src,
          (void*)(&bsm[c & 1][id*512]), 16, 0, 0);
    }
  };
  auto STAGE1 = [&](int c){
    #pragma unroll
    for (int i=0;i<8;i++){
      int id = w*8 + i;
      int hl  = id & 1;
      int q   = (id >> 1) & 3;
      int wu2 = (id >> 3) & 1;
      int ksl = id >> 4;
      int ks  = c*4 + ksl;
      const unsigned short* src = (hl ? w1l : w1h)
          + (((size_t)(q*32 + by*2 + wu2)*32 + ks)*64 + lane)*8;
      __builtin_amdgcn_global_load_lds((const void*)src,
          (void*)(&bsm[c & 1][id*512]), 16, 0, 0);
    }
  };

  float c0r[4] = {0.f,0.f,0.f,0.f};
  float c1r[4] = {0.f,0.f,0.f,0.f};
  const f32x4 z4 = {0.f,0.f,0.f,0.f};

  STAGE0(0);
  for (int t=0;t<TDEC;t++){
    const unsigned short* h0ih = (t&1)? h0hb : h0ha;
    const unsigned short* h0il = (t&1)? h0lb : h0la;
    unsigned short* h0oh = (t&1)? h0ha : h0hb;
    unsigned short* h0ol = (t&1)? h0la : h0lb;
    const unsigned short* h1ih = (t&1)? h1hb : h1ha;
    const unsigned short* h1il = (t&1)? h1lb : h1la;
    unsigned short* h1oh = (t&1)? h1ha : h1hb;
    unsigned short* h1ol = (t&1)? h1la : h1lb;

    // -------- phase A: generator layer 0 (staged) --------
    {
      __syncthreads();   // chunk 0 resident (vmcnt drained)
      const unsigned short* pah = h0ih + (size_t)arow*512 + kgrp*8;
      const unsigned short* pal = h0il + (size_t)arow*512 + kgrp*8;
      f32x4 aHH[4]={z4,z4,z4,z4}, aLH[4]={z4,z4,z4,z4}, aHL[4]={z4,z4,z4,z4};
      for (int c=0; c<4; c++){
        if (c < 3) STAGE0(c+1); else STAGE1(0);
        const unsigned short* bb = &bsm[c&1][0];
        #pragma unroll
        for (int ksl=0; ksl<4; ksl++){
          int ks = c*4 + ksl;
          bf16x8 ah = *(const bf16x8*)(pah + (size_t)ks*32);
          bf16x8 al = *(const bf16x8*)(pal + (size_t)ks*32);
          #pragma unroll
          for (int q=0;q<4;q++){
            int fid = ((ksl*2 + wu)*4 + q)*2;
            bf16x8 bh = *(const bf16x8*)(bb + fid*512     + lane*8);
            bf16x8 bl = *(const bf16x8*)(bb + fid*512+512 + lane*8);
            aHH[q] = __builtin_amdgcn_mfma_f32_16x16x32_bf16(ah, bh, aHH[q], 0,0,0);
            aLH[q] = __builtin_amdgcn_mfma_f32_16x16x32_bf16(al, bh, aLH[q], 0,0,0);
            aHL[q] = __builtin_amdgcn_mfma_f32_16x16x32_bf16(ah, bl, aHL[q], 0,0,0);
          }
        }
        __syncthreads();
      }

      // ---- logits of step t-1 (block-local, from h1 prev) + argmax ----
      int tkr[4] = {0,0,0,0};
      if (t > 0){
        float acc5[4][5];
        #pragma unroll
        for (int r=0;r<4;r++){
          #pragma unroll
          for (int v=0;v<5;v++) acc5[r][v]=0.f;
        }
        #pragma unroll
        for (int j=0;j<4;j++){
          const int ub = lo16*32 + j*8;
          f32x4 w0[5], w1[5];
          #pragma unroll
          for (int v=0;v<5;v++){
            const float* wp = outW + v*512 + ub;
            w0[v] = *(const f32x4*)(wp);
            w1[v] = *(const f32x4*)(wp+4);
          }
          #pragma unroll
          for (int r=0;r<4;r++){
            const unsigned short* hh = h1ih + (size_t)(r0+r)*512 + ub;
            const unsigned short* hl = h1il + (size_t)(r0+r)*512 + ub;
            bf16x8 vh = *(const bf16x8*)hh;
            bf16x8 vl = *(const bf16x8*)hl;
            #pragma unroll
            for (int m=0;m<4;m++){
              float hv = bf2f((unsigned short)vh[m]) + bf2f((unsigned short)vl[m]);
              #pragma unroll
              for (int v=0;v<5;v++) acc5[r][v] += hv * w0[v][m];
            }
            #pragma unroll
            for (int m=0;m<4;m++){
              float hv = bf2f((unsigned short)vh[m+4]) + bf2f((unsigned short)vl[m+4]);
              #pragma unroll
              for (int v=0;v<5;v++) acc5[r][v] += hv * w1[v][m];
            }
          }
        }
        #pragma unroll
        for (int r=0;r<4;r++){
          #pragma unroll
          for (int v=0;v<5;v++){
            float s = acc5[r][v];
            s += __shfl_xor(s, 1);
            s += __shfl_xor(s, 2);
            s += __shfl_xor(s, 4);
            s += __shfl_xor(s, 8);
            acc5[r][v] = s + outb[v];
          }
          float best = acc5[r][0]; int tk = 0;
          if (acc5[r][1] > best){ best = acc5[r][1]; tk = 1; }
          if (acc5[r][2] > best){ best = acc5[r][2]; tk = 2; }
          if (acc5[r][3] > best){ best = acc5[r][3]; tk = 3; }
          if (acc5[r][4] > best){ best = acc5[r][4]; tk = 4; }
          tkr[r] = tk;
        }
        if (by == 0 && wu == 0 && lo16 == 0){
          #pragma unroll
          for (int r=0;r<4;r++){
            float* op = out + ((size_t)(r0+r)*TDEC + (t-1))*5;
            #pragma unroll
            for (int v=0;v<5;v++) op[v] = acc5[r][v];
          }
        }
      }

      #pragma unroll
      for (int r=0;r<4;r++){
        const int e = r0 + r;
        const float* ep = egen0 + (size_t)tkr[r]*2048 + u;
        float zi = aHH[0][r]+aLH[0][r]+aHL[0][r] + ep[0];
        float zf = aHH[1][r]+aLH[1][r]+aHL[1][r] + ep[512];
        float zg = aHH[2][r]+aLH[2][r]+aHL[2][r] + ep[1024];
        float zo = aHH[3][r]+aLH[3][r]+aHL[3][r] + ep[1536];
        float c = sigf(zf)*c0r[r] + sigf(zi)*tanhf(zg);
        float h = sigf(zo)*tanhf(c);
        c0r[r] = c;
        const size_t idx = (size_t)e*512 + u;
        unsigned short hb = f2bf(h);
        h0oh[idx] = hb;
        h0ol[idx] = f2bf(h - bf2f(hb));
      }
    }
    grid.sync();

    // -------- phase B: generator layer 1 (staged) --------
    {
      const unsigned short* pxh = h0oh + (size_t)arow*512 + kgrp*8;
      const unsigned short* pxl = h0ol + (size_t)arow*512 + kgrp*8;
      const unsigned short* pah = h1ih + (size_t)arow*512 + kgrp*8;
      const unsigned short* pal = h1il + (size_t)arow*512 + kgrp*8;
      f32x4 aHH[4]={z4,z4,z4,z4}, aLH[4]={z4,z4,z4,z4}, aHL[4]={z4,z4,z4,z4};
      for (int c=0; c<8; c++){
        if (c < 7) STAGE1(c+1);
        else if (t+1 < TDEC) STAGE0(0);
        const unsigned short* bb = &bsm[c&1][0];
        const unsigned short* pAh = (c < 4) ? pxh : pah;
        const unsigned short* pAl = (c < 4) ? pxl : pal;
        const int ksA = (c & 3)*4;
        #pragma unroll
        for (int ksl=0; ksl<4; ksl++){
          bf16x8 ah = *(const bf16x8*)(pAh + (size_t)(ksA+ksl)*32);
          bf16x8 al = *(const bf16x8*)(pAl + (size_t)(ksA+ksl)*32);
          #pragma unroll
          for (int q=0;q<4;q++){
            int fid = ((ksl*2 + wu)*4 + q)*2;
            bf16x8 bh = *(const bf16x8*)(bb + fid*512     + lane*8);
            bf16x8 bl = *(const bf16x8*)(bb + fid*512+512 + lane*8);
            aHH[q] = __builtin_amdgcn_mfma_f32_16x16x32_bf16(ah, bh, aHH[q], 0,0,0);
            aLH[q] = __builtin_amdgcn_mfma_f32_16x16x32_bf16(al, bh, aLH[q], 0,0,0);
            aHL[q] = __builtin_amdgcn_mfma_f32_16x16x32_bf16(ah, bl, aHL[q], 0,0,0);
          }
        }
        __syncthreads();
      }

      #pragma unroll
      for (int r=0;r<4;r++){
        const int e = r0 + r;
        float zi = aHH[0][r]+aLH[0][r]+aHL[0][r] + b10;
        float zf = aHH[1][r]+aLH[1][r]+aHL[1][r] + b11;
        float zg = aHH[2][r]+aLH[2][r]+aHL[2][r] + b12;
        float zo = aHH[3][r]+aLH[3][r]+aHL[3][r] + b13;
        float c = sigf(zf)*c1r[r] + sigf(zi)*tanhf(zg);
        float h = sigf(zo)*tanhf(c);
        c1r[r] = c;
        const size_t idx = (size_t)e*512 + u;
        unsigned short hb = f2bf(h);
        h1oh[idx] = hb;
        h1ol[idx] = f2bf(h - bf2f(hb));
      }
    }
    grid.sync();
  }
}

// final-step logits (t = TDEC-1): one wave per batch elem
__global__ void dec_outF(const unsigned short* __restrict__ h1h,
                         const unsigned short* __restrict__ h1l,
                         const float* __restrict__ outW,
                         const float* __restrict__ outb,
                         float* __restrict__ out){
  const int lane = threadIdx.x & 63;
  const int e = blockIdx.x*4 + (threadIdx.x >> 6);
  const unsigned short* hh = h1h + (size_t)e*512;
  const unsigned short* hl = h1l + (size_t)e*512;
  float s0=0,s1=0,s2=0,s3=0,s4=0;
  for (int k=lane;k<512;k+=64){
    float hv = bf2f(hh[k]) + bf2f(hl[k]);
    s0 += hv*outW[k];
    s1 += hv*outW[512+k];
    s2 += hv*outW[1024+k];
    s3 += hv*outW[1536+k];
    s4 += hv*outW[2048+k];
  }
  #pragma unroll
  for (int off=32; off>0; off>>=1){
    s0 += __shfl_down(s0, off);
    s1 += __shfl_down(s1, off);
    s2 += __shfl_down(s2, off);
    s3 += __shfl_down(s3, off);
    s4 += __shfl_down(s4, off);
  }
  if (lane==0){
    float* op = out + ((size_t)e*TDEC + (TDEC-1))*5;
    op[0]=s0+outb[0]; op[1]=s1+outb[1]; op[2]=s2+outb[2];
    op[3]=s3+outb[3]; op[4]=s4+outb[4];
  }
}

extern "C" void kernel_launch(void* const* d_in, const int* in_sizes, int n_in,
                              void* d_out, int out_size, void* d_ws, size_t ws_size,
                              hipStream_t stream){
  (void)in_sizes; (void)n_in; (void)out_size;
  const int*   leftc    = (const int*)d_in[0];
  const int*   rightc   = (const int*)d_in[1];
  const float* emb      = (const float*)d_in[3];
  const float* ctx0_Wih = (const float*)d_in[4];
  const float* ctx0_Whh = (const float*)d_in[5];
  const float* ctx0_b   = (const float*)d_in[6];
  const float* ctx1_Wih = (const float*)d_in[7];
  const float* ctx1_Whh = (const float*)d_in[8];
  const float* ctx1_b   = (const float*)d_in[9];
  const float* gen0_Wih = (const float*)d_in[10];
  const float* gen0_Whh = (const float*)d_in[11];
  const float* gen0_b   = (const float*)d_in[12];
  const float* gen1_Wih = (const float*)d_in[13];
  const float* gen1_Whh = (const float*)d_in[14];
  const float* gen1_b   = (const float*)d_in[15];
  const float* out_W    = (const float*)d_in[16];
  const float* out_b    = (const float*)d_in[17];
  float* out = (float*)d_out;

  char* p = (char*)d_ws;
  auto carve = [&](size_t nfloats)->float*{
    float* r = (float*)p;
    p += ((nfloats*sizeof(float) + 255) & ~(size_t)255);
    return r;
  };
  auto carveu = [&](size_t nush)->unsigned short*{
    return (unsigned short*)carve((nush + 1)/2);
  };
  float* ectx0  = carve(2*5*1024);
  float* egen0  = carve(5*2048);
  float* leftF  = carve((size_t)BATCH*HG);
  float* rightF = carve((size_t)BATCH*HG);
  unsigned short* c0pkh = carveu((size_t)2*1024*256);
  unsigned short* c0pkl = carveu((size_t)2*1024*256);
  unsigned short* c1pkh = carveu((size_t)2*1024*768);
  unsigned short* c1pkl = carveu((size_t)2*1024*768);
  unsigned short* pk0h = carveu((size_t)2048*512);
  unsigned short* pk0l = carveu((size_t)2048*512);
  unsigned short* pk1h = carveu((size_t)2048*1024);
  unsigned short* pk1l = carveu((size_t)2048*1024);
  unsigned short* h0ha = carveu((size_t)BATCH*HG);
  unsigned short* h0la = carveu((size_t)BATCH*HG);
  unsigned short* h0hb = carveu((size_t)BATCH*HG);
  unsigned short* h0lb = carveu((size_t)BATCH*HG);
  unsigned short* h1ha = carveu((size_t)BATCH*HG);
  unsigned short* h1la = carveu((size_t)BATCH*HG);
  unsigned short* h1hb = carveu((size_t)BATCH*HG);
  unsigned short* h1lb = carveu((size_t)BATCH*HG);
  unsigned short* y0h = carveu((size_t)L_SEQ*BATCH*512);   // 105 MB
  unsigned short* y0l = carveu((size_t)L_SEQ*BATCH*512);   // 105 MB
  if ((size_t)(p - (char*)d_ws) > ws_size) return;  // insufficient workspace -> loud fail

  // weight packs (fragment-linear bf16 hi/lo)
  for (int d=0; d<2; d++){
    pack_w<<<128, 256, 0, stream>>>(ctx0_Whh + (size_t)d*1024*256, 1024, 256, 8, 0,
                                    c0pkh + (size_t)d*262144, c0pkl + (size_t)d*262144);
    pack_w<<<256, 256, 0, stream>>>(ctx1_Wih + (size_t)d*1024*512, 1024, 512, 24, 0,
                                    c1pkh + (size_t)d*786432, c1pkl + (size_t)d*786432);
    pack_w<<<128, 256, 0, stream>>>(ctx1_Whh + (size_t)d*1024*256, 1024, 256, 24, 16,
                                    c1pkh + (size_t)d*786432, c1pkl + (size_t)d*786432);
  }
  pack_w<<<512, 256, 0, stream>>>(gen0_Whh, 2048, 512, 16,  0, pk0h, pk0l);
  pack_w<<<512, 256, 0, stream>>>(gen1_Wih, 2048, 512, 32,  0, pk1h, pk1l);
  pack_w<<<512, 256, 0, stream>>>(gen1_Whh, 2048, 512, 32, 16, pk1h, pk1l);

  embprep<<<(20480+255)/256, 256, 0, stream>>>(emb, ctx0_Wih, ctx0_b,
                                               gen0_Wih, gen0_b, ectx0, egen0);

  // left encode (finals at t=99), then right (finals at t=0); y0 reused
  ctx_l0_mfma<<<128, 512, 0, stream>>>(leftc, ectx0, c0pkh, c0pkl, y0h, y0l);
  ctx_l1_mfma<<<128, 512, 0, stream>>>(y0h, y0l, c1pkh, c1pkl, ctx1_b, leftF, L_SEQ-1);
  ctx_l0_mfma<<<128, 512, 0, stream>>>(rightc, ectx0, c0pkh, c0pkl, y0h, y0l);
  ctx_l1_mfma<<<128, 512, 0, stream>>>(y0h, y0l, c1pkh, c1pkl, ctx1_b, rightF, 0);

  combine_init2<<<(BATCH*HG+255)/256, 256, 0, stream>>>(leftF, rightF,
                                                        h0ha, h0la, h1ha, h1la);

  void* kargs[] = {
    (void*)&egen0, (void*)&pk0h, (void*)&pk0l, (void*)&pk1h, (void*)&pk1l,
    (void*)&gen1_b, (void*)&out_W, (void*)&out_b,
    (void*)&h0ha, (void*)&h0la, (void*)&h0hb, (void*)&h0lb,
    (void*)&h1ha, (void*)&h1la, (void*)&h1hb, (void*)&h1lb,
    (void*)&out
  };
  hipLaunchCooperativeKernel((void*)dec_persist, dim3(256), dim3(512),
                             kargs, 0, stream);

  // t = TDEC-1 logits (h1 final lives in the 'a' buffers after odd t=255)
  dec_outF<<<256, 256, 0, stream>>>(h1ha, h1la, out_W, out_b, out);
}

// Round 10
// 22947.995 us; speedup vs baseline: 1.9339x; 1.9339x over previous
//
#include <hip/hip_runtime.h>

// LSTMGapFiller R11: decoder = R9 verbatim (23.0ms proven; R10's counters
// proved grid.sync scatters L2 invalidates -> 108 MB/step refetch, fetch-bound
// at 427-894 GB/s; persistence is structurally wrong here). New: left+right
// context encodes merged into single 256-block launches (was 4x 128-block =
// half the GPU idle). Second y0 buffer (+210MB) carved only if workspace
// allows; otherwise automatic fallback to the sequential 4-launch path
// (force_side param). dir stays at blockIdx bit2 -> XCD L2 mapping preserved.

#define L_SEQ 100
#define BATCH 1024
#define HCTX 256
#define HG 512
#define TDEC 256

typedef __attribute__((ext_vector_type(8))) short bf16x8;
typedef __attribute__((ext_vector_type(4))) float f32x4;

__device__ __forceinline__ float sigf(float x){ return 1.0f/(1.0f+expf(-x)); }
__device__ __forceinline__ unsigned short f2bf(float x){
  unsigned int u = __float_as_uint(x);
  return (unsigned short)((u + 0x7fffu + ((u>>16)&1u)) >> 16);   // RNE
}
__device__ __forceinline__ float bf2f(unsigned short h){
  return __uint_as_float(((unsigned int)h)<<16);
}

// Pack W[G][K] (fp32, row-major) into MFMA-fragment-linear bf16 hi/lo.
__global__ void pack_w(const float* __restrict__ W, int G, int K, int KTtot, int kt0,
                       unsigned short* __restrict__ hi, unsigned short* __restrict__ lo){
  int idx = blockIdx.x*blockDim.x + threadIdx.x;
  int kt_n = K/32;
  int total = (G/16)*kt_n*64;
  if (idx >= total) return;
  int lane = idx & 63;
  int ktl = (idx>>6) % kt_n;
  int gt  = (idx>>6) / kt_n;
  int g = gt*16 + (lane & 15);
  int k = ktl*32 + (lane>>4)*8;
  const float* src = W + (size_t)g*K + k;
  size_t dst = (((size_t)gt*KTtot + (kt0 + ktl))*64 + lane)*8;
  #pragma unroll
  for (int j=0;j<8;j++){
    float x = src[j];
    unsigned short h = f2bf(x);
    hi[dst+j] = h;
    lo[dst+j] = f2bf(x - bf2f(h));
  }
}

// embedding projections (vocab=5)
__global__ void embprep(const float* __restrict__ emb,
                        const float* __restrict__ c0Wih, const float* __restrict__ c0b,
                        const float* __restrict__ g0Wih, const float* __restrict__ g0b,
                        float* __restrict__ ectx0, float* __restrict__ egen0){
  int idx = blockIdx.x*blockDim.x + threadIdx.x;
  if (idx < 2*5*1024){
    int d = idx / 5120;
    int v = (idx / 1024) % 5;
    int j = idx % 1024;
    const float* w = c0Wih + ((size_t)d*1024 + j)*64;
    const float* e = emb + v*64;
    float s = c0b[d*1024 + j];
    #pragma unroll
    for (int k=0;k<64;k++) s += e[k]*w[k];
    ectx0[idx] = s;
  } else if (idx < 2*5*1024 + 5*2048){
    int i2 = idx - 10240;
    int v = i2 / 2048;
    int j = i2 % 2048;
    const float* w = g0Wih + (size_t)j*64;
    const float* e = emb + v*64;
    float s = g0b[j];
    #pragma unroll
    for (int k=0;k<64;k++) s += e[k]*w[k];
    egen0[i2] = s;
  }
}

// ---------------- context layer 0 (MFMA, both sides) ------------------------
// merged (force_side<0): grid 256, side=(id>>3)&1. fallback: grid 128,
// side=force_side, old bx mapping. dir at bit2 -> XCD L2 locality either way.
__global__ void __launch_bounds__(512,1) ctx_l0_mfma(
    const int* __restrict__ toksL, const int* __restrict__ toksR,
    const float* __restrict__ ectx0,
    const unsigned short* __restrict__ wh, const unsigned short* __restrict__ wl,
    unsigned short* __restrict__ y0Lh, unsigned short* __restrict__ y0Ll,
    unsigned short* __restrict__ y0Rh, unsigned short* __restrict__ y0Rl,
    int force_side)
{
  const int id  = blockIdx.x;
  int dir, side, bx;
  if (force_side < 0){
    dir = (id >> 2) & 1; side = (id >> 3) & 1;
    bx = ((id >> 4) << 2) | (id & 3);
  } else {
    dir = (id >> 2) & 1; side = force_side;
    bx = ((id >> 3) << 2) | (id & 3);
  }
  const int* toks = side ? toksR : toksL;
  unsigned short* y0h = side ? y0Rh : y0Lh;
  unsigned short* y0l = side ? y0Rl : y0Ll;
  const int e0  = bx * 16;
  const int lane = threadIdx.x & 63;
  const int w    = threadIdx.x >> 6;
  const int lo16 = lane & 15, kgrp = lane >> 4;

  __shared__ unsigned short hsh[16*256];
  __shared__ unsigned short hsl[16*256];
  __shared__ float cs[16*256];
  for (int i=threadIdx.x;i<16*256;i+=512){ hsh[i]=0; hsl[i]=0; cs[i]=0.f; }
  __syncthreads();

  const unsigned short* pbh[4][2];
  const unsigned short* pbl[4][2];
  #pragma unroll
  for (int g=0;g<4;g++){
    #pragma unroll
    for (int st=0;st<2;st++){
      int ct = g*16 + w*2 + st;
      size_t off = (size_t)dir*1024*256 + ((size_t)(ct*8)*64 + lane)*8;
      pbh[g][st] = wh + off; pbl[g][st] = wl + off;
    }
  }
  const unsigned aoff0 = (unsigned)(lo16*512 + kgrp*16);
  const unsigned axor  = ((unsigned)(lo16 & 7)) << 4;

  for (int s=0;s<L_SEQ;s++){
    const int t = dir ? (L_SEQ-1-s) : s;
    f32x4 zero = {0.f,0.f,0.f,0.f};
    f32x4 acc[4][2];
    #pragma unroll
    for (int g=0;g<4;g++){
      #pragma unroll
      for (int st=0;st<2;st++) acc[g][st] = zero;
    }
    #pragma unroll 2
    for (int kt=0;kt<8;kt++){
      unsigned ao = (aoff0 + kt*64) ^ axor;
      bf16x8 ah = *(const bf16x8*)((const char*)hsh + ao);
      bf16x8 al = *(const bf16x8*)((const char*)hsl + ao);
      #pragma unroll
      for (int g=0;g<4;g++){
        #pragma unroll
        for (int st=0;st<2;st++){
          bf16x8 bh = *(const bf16x8*)(pbh[g][st] + (size_t)kt*512);
          bf16x8 bl = *(const bf16x8*)(pbl[g][st] + (size_t)kt*512);
          acc[g][st] = __builtin_amdgcn_mfma_f32_16x16x32_bf16(ah,bh,acc[g][st],0,0,0);
          acc[g][st] = __builtin_amdgcn_mfma_f32_16x16x32_bf16(al,bh,acc[g][st],0,0,0);
          acc[g][st] = __builtin_amdgcn_mfma_f32_16x16x32_bf16(ah,bl,acc[g][st],0,0,0);
        }
      }
    }
    __syncthreads();
    int tkr[4];
    #pragma unroll
    for (int r=0;r<4;r++) tkr[r] = toks[(e0 + kgrp*4 + r)*L_SEQ + t];
    #pragma unroll
    for (int st=0;st<2;st++){
      const int unit = w*32 + st*16 + lo16;
      #pragma unroll
      for (int r=0;r<4;r++){
        const int row = kgrp*4 + r;
        const int e = e0 + row;
        const float* ep = ectx0 + ((size_t)(dir*5 + tkr[r]))*1024 + unit;
        float zi = acc[0][st][r] + ep[0];
        float zf = acc[1][st][r] + ep[256];
        float zg = acc[2][st][r] + ep[512];
        float zo = acc[3][st][r] + ep[768];
        int ci = row*256 + unit;
        float c = sigf(zf)*cs[ci] + sigf(zi)*tanhf(zg);
        float h = sigf(zo)*tanhf(c);
        cs[ci] = c;
        unsigned short hb = f2bf(h), lb = f2bf(h - bf2f(hb));
        unsigned hoff = ((unsigned)(row*512 + unit*2)) ^ (((unsigned)(row & 7)) << 4);
        *(unsigned short*)((char*)hsh + hoff) = hb;
        *(unsigned short*)((char*)hsl + hoff) = lb;
        size_t yo = ((size_t)t*BATCH + e)*512 + dir*256 + unit;
        y0h[yo] = hb; y0l[yo] = lb;
      }
    }
    __syncthreads();
  }
}

// ---------------- context layer 1 (MFMA, both sides) ------------------------
__global__ void __launch_bounds__(512,1) ctx_l1_mfma(
    const unsigned short* __restrict__ y0Lh, const unsigned short* __restrict__ y0Ll,
    const unsigned short* __restrict__ y0Rh, const unsigned short* __restrict__ y0Rl,
    const unsigned short* __restrict__ wh, const unsigned short* __restrict__ wl,
    const float* __restrict__ bias,
    float* __restrict__ leftF, float* __restrict__ rightF,
    int force_side)
{
  const int id  = blockIdx.x;
  int dir, side, bx;
  if (force_side < 0){
    dir = (id >> 2) & 1; side = (id >> 3) & 1;
    bx = ((id >> 4) << 2) | (id & 3);
  } else {
    dir = (id >> 2) & 1; side = force_side;
    bx = ((id >> 3) << 2) | (id & 3);
  }
  const unsigned short* y0h = side ? y0Rh : y0Lh;
  const unsigned short* y0l = side ? y0Rl : y0Ll;
  float* finals = side ? rightF : leftF;
  const int t_store = side ? 0 : (L_SEQ-1);
  const int e0  = bx * 16;
  const int lane = threadIdx.x & 63;
  const int w    = threadIdx.x >> 6;
  const int lo16 = lane & 15, kgrp = lane >> 4;

  __shared__ unsigned short xsh[16*512];
  __shared__ unsigned short xsl[16*512];
  __shared__ unsigned short hsh[16*256];
  __shared__ unsigned short hsl[16*256];
  __shared__ float cs[16*256];
  for (int i=threadIdx.x;i<16*256;i+=512){ hsh[i]=0; hsl[i]=0; cs[i]=0.f; }

  float bb[4][2];
  #pragma unroll
  for (int g=0;g<4;g++){
    #pragma unroll
    for (int st=0;st<2;st++)
      bb[g][st] = bias[dir*1024 + g*256 + w*32 + st*16 + lo16];
  }
  const unsigned short* pbh[4][2];
  const unsigned short* pbl[4][2];
  #pragma unroll
  for (int g=0;g<4;g++){
    #pragma unroll
    for (int st=0;st<2;st++){
      int ct = g*16 + w*2 + st;
      size_t off = (size_t)dir*1024*768 + ((size_t)(ct*24)*64 + lane)*8;
      pbh[g][st] = wh + off; pbl[g][st] = wl + off;
    }
  }
  const unsigned axor = ((unsigned)(lo16 & 7)) << 4;
  __syncthreads();

  for (int s=0;s<L_SEQ;s++){
    const int t = dir ? (L_SEQ-1-s) : s;
    #pragma unroll
    for (int cc=0; cc<2; cc++){
      int ci = threadIdx.x + cc*512;
      int row = ci >> 6, cr = ci & 63;
      const unsigned short* srcbase = y0h + ((size_t)t*BATCH + e0 + row)*512 + cr*8;
      const unsigned short* srcbasel = y0l + ((size_t)t*BATCH + e0 + row)*512 + cr*8;
      uint4 vh = *(const uint4*)srcbase;
      uint4 vl = *(const uint4*)srcbasel;
      unsigned xo = ((unsigned)(row*1024 + cr*16)) ^ (((unsigned)(row & 7)) << 4);
      *(uint4*)((char*)xsh + xo) = vh;
      *(uint4*)((char*)xsl + xo) = vl;
    }
    __syncthreads();
    f32x4 zero = {0.f,0.f,0.f,0.f};
    f32x4 acc[4][2];
    #pragma unroll
    for (int g=0;g<4;g++){
      #pragma unroll
      for (int st=0;st<2;st++) acc[g][st] = zero;
    }
    #pragma unroll 2
    for (int kt=0;kt<16;kt++){
      unsigned ao = ((unsigned)(lo16*1024 + kt*64 + kgrp*16)) ^ axor;
      bf16x8 ah = *(const bf16x8*)((const char*)xsh + ao);
      bf16x8 al = *(const bf16x8*)((const char*)xsl + ao);
      #pragma unroll
      for (int g=0;g<4;g++){
        #pragma unroll
        for (int st=0;st<2;st++){
          bf16x8 bh = *(const bf16x8*)(pbh[g][st] + (size_t)kt*512);
          bf16x8 bl = *(const bf16x8*)(pbl[g][st] + (size_t)kt*512);
          acc[g][st] = __builtin_amdgcn_mfma_f32_16x16x32_bf16(ah,bh,acc[g][st],0,0,0);
          acc[g][st] = __builtin_amdgcn_mfma_f32_16x16x32_bf16(al,bh,acc[g][st],0,0,0);
          acc[g][st] = __builtin_amdgcn_mfma_f32_16x16x32_bf16(ah,bl,acc[g][st],0,0,0);
        }
      }
    }
    #pragma unroll 2
    for (int kt=16;kt<24;kt++){
      unsigned ao = ((unsigned)(lo16*512 + (kt-16)*64 + kgrp*16)) ^ axor;
      bf16x8 ah = *(const bf16x8*)((const char*)hsh + ao);
      bf16x8 al = *(const bf16x8*)((const char*)hsl + ao);
      #pragma unroll
      for (int g=0;g<4;g++){
        #pragma unroll
        for (int st=0;st<2;st++){
          bf16x8 bh = *(const bf16x8*)(pbh[g][st] + (size_t)kt*512);
          bf16x8 bl = *(const bf16x8*)(pbl[g][st] + (size_t)kt*512);
          acc[g][st] = __builtin_amdgcn_mfma_f32_16x16x32_bf16(ah,bh,acc[g][st],0,0,0);
          acc[g][st] = __builtin_amdgcn_mfma_f32_16x16x32_bf16(al,bh,acc[g][st],0,0,0);
          acc[g][st] = __builtin_amdgcn_mfma_f32_16x16x32_bf16(ah,bl,acc[g][st],0,0,0);
        }
      }
    }
    __syncthreads();
    #pragma unroll
    for (int st=0;st<2;st++){
      const int unit = w*32 + st*16 + lo16;
      #pragma unroll
      for (int r=0;r<4;r++){
        const int row = kgrp*4 + r;
        float zi = acc[0][st][r] + bb[0][st];
        float zf = acc[1][st][r] + bb[1][st];
        float zg = acc[2][st][r] + bb[2][st];
        float zo = acc[3][st][r] + bb[3][st];
        int ci = row*256 + unit;
        float c = sigf(zf)*cs[ci] + sigf(zi)*tanhf(zg);
        float h = sigf(zo)*tanhf(c);
        cs[ci] = c;
        unsigned short hb = f2bf(h), lb = f2bf(h - bf2f(hb));
        unsigned hoff = ((unsigned)(row*512 + unit*2)) ^ (((unsigned)(row & 7)) << 4);
        *(unsigned short*)((char*)hsh + hoff) = hb;
        *(unsigned short*)((char*)hsl + hoff) = lb;
        if (t == t_store)
          finals[(size_t)(e0 + row)*512 + dir*256 + unit] = h;
      }
    }
    __syncthreads();
  }
}

__global__ void combine_init2(const float* __restrict__ lf, const float* __restrict__ rf,
                              unsigned short* __restrict__ h0h, unsigned short* __restrict__ h0l,
                              unsigned short* __restrict__ h1h, unsigned short* __restrict__ h1l,
                              float* __restrict__ c0, float* __restrict__ c1){
  int i = blockIdx.x*blockDim.x + threadIdx.x;
  if (i < BATCH*HG){
    float v = 0.5f*(lf[i]+rf[i]);
    unsigned short h = f2bf(v);
    unsigned short l = f2bf(v - bf2f(h));
    h0h[i]=h; h0l[i]=l; h1h[i]=h; h1l[i]=l;
    c0[i]=0.f; c1[i]=0.f;
  }
}

// ------------- decoder layer 0 (staged MFMA + block-local logits/argmax) ----
// R9 verbatim. 256 blocks x 512 thr = 1 block/CU; B staged via global_load_lds.
__global__ void __launch_bounds__(512,1) dec_l0_mfma(
    const float* __restrict__ egen0,
    const unsigned short* __restrict__ wh, const unsigned short* __restrict__ wl,
    const unsigned short* __restrict__ hih, const unsigned short* __restrict__ hil,
    const unsigned short* __restrict__ h1ih, const unsigned short* __restrict__ h1il,
    unsigned short* __restrict__ hoh, unsigned short* __restrict__ hol,
    float* __restrict__ cst,
    const float* __restrict__ outW, const float* __restrict__ outb,
    float* __restrict__ out, int t)
{
  __shared__ unsigned short bsm[2][32768];    // 2 x 64 KB chunks
  const int bid = blockIdx.x;
  const int by = bid & 15;
  const int bx = bid >> 4;
  const int e0 = bx * 64;
  const int lane = threadIdx.x & 63;
  const int w = threadIdx.x >> 6;
  const int wm = w & 3, wu = w >> 2;
  const int ut = by*2 + wu;
  const int lo16 = lane & 15, kgrp = lane >> 4;
  const int arow = e0 + wm*16 + lo16;
  const int u = ut*16 + lo16;
  const int r0 = e0 + wm*16 + kgrp*4;

  const unsigned short* pah = hih + (size_t)arow*512 + kgrp*8;
  const unsigned short* pal = hil + (size_t)arow*512 + kgrp*8;

  auto STAGE = [&](int c){
    #pragma unroll
    for (int i=0;i<8;i++){
      int id = w*8 + i;
      int hl  = id & 1;
      int q   = (id >> 1) & 3;
      int wu2 = (id >> 3) & 1;
      int ksl = id >> 4;
      int ks  = c*4 + ksl;
      const unsigned short* src = (hl ? wl : wh)
          + (((size_t)(q*32 + by*2 + wu2)*16 + ks)*64 + lane)*8;
      __builtin_amdgcn_global_load_lds((const void*)src,
          (void*)(&bsm[c & 1][id*512]), 16, 0, 0);
    }
  };

  const f32x4 z4 = {0.f,0.f,0.f,0.f};
  f32x4 aHH[4]={z4,z4,z4,z4}, aLH[4]={z4,z4,z4,z4}, aHL[4]={z4,z4,z4,z4};

  STAGE(0);
  __syncthreads();
  for (int c=0; c<4; c++){
    if (c+1 < 4) STAGE(c+1);
    const unsigned short* bb = &bsm[c&1][0];
    #pragma unroll
    for (int ksl=0; ksl<4; ksl++){
      int ks = c*4 + ksl;
      bf16x8 ah = *(const bf16x8*)(pah + (size_t)ks*32);
      bf16x8 al = *(const bf16x8*)(pal + (size_t)ks*32);
      #pragma unroll
      for (int q=0;q<4;q++){
        int fid = ((ksl*2 + wu)*4 + q)*2;
        bf16x8 bh = *(const bf16x8*)(bb + fid*512     + lane*8);
        bf16x8 bl = *(const bf16x8*)(bb + fid*512+512 + lane*8);
        aHH[q] = __builtin_amdgcn_mfma_f32_16x16x32_bf16(ah, bh, aHH[q], 0,0,0);
        aLH[q] = __builtin_amdgcn_mfma_f32_16x16x32_bf16(al, bh, aLH[q], 0,0,0);
        aHL[q] = __builtin_amdgcn_mfma_f32_16x16x32_bf16(ah, bl, aHL[q], 0,0,0);
      }
    }
    __syncthreads();
  }

  // ---- logits of step t-1 for rows r0..r0+3, per 16-lane group ----
  int tkr[4] = {0,0,0,0};
  if (t > 0){
    float acc5[4][5];
    #pragma unroll
    for (int r=0;r<4;r++){
      #pragma unroll
      for (int v=0;v<5;v++) acc5[r][v]=0.f;
    }
    #pragma unroll
    for (int j=0;j<4;j++){
      const int ub = lo16*32 + j*8;
      f32x4 w0[5], w1[5];
      #pragma unroll
      for (int v=0;v<5;v++){
        const float* wp = outW + v*512 + ub;
        w0[v] = *(const f32x4*)(wp);
        w1[v] = *(const f32x4*)(wp+4);
      }
      #pragma unroll
      for (int r=0;r<4;r++){
        const unsigned short* hh = h1ih + (size_t)(r0+r)*512 + ub;
        const unsigned short* hl = h1il + (size_t)(r0+r)*512 + ub;
        bf16x8 vh = *(const bf16x8*)hh;
        bf16x8 vl = *(const bf16x8*)hl;
        #pragma unroll
        for (int m=0;m<4;m++){
          float hv = bf2f((unsigned short)vh[m]) + bf2f((unsigned short)vl[m]);
          #pragma unroll
          for (int v=0;v<5;v++) acc5[r][v] += hv * w0[v][m];
        }
        #pragma unroll
        for (int m=0;m<4;m++){
          float hv = bf2f((unsigned short)vh[m+4]) + bf2f((unsigned short)vl[m+4]);
          #pragma unroll
          for (int v=0;v<5;v++) acc5[r][v] += hv * w1[v][m];
        }
      }
    }
    #pragma unroll
    for (int r=0;r<4;r++){
      #pragma unroll
      for (int v=0;v<5;v++){
        float s = acc5[r][v];
        s += __shfl_xor(s, 1);
        s += __shfl_xor(s, 2);
        s += __shfl_xor(s, 4);
        s += __shfl_xor(s, 8);
        acc5[r][v] = s + outb[v];
      }
      float best = acc5[r][0]; int tk = 0;
      if (acc5[r][1] > best){ best = acc5[r][1]; tk = 1; }
      if (acc5[r][2] > best){ best = acc5[r][2]; tk = 2; }
      if (acc5[r][3] > best){ best = acc5[r][3]; tk = 3; }
      if (acc5[r][4] > best){ best = acc5[r][4]; tk = 4; }
      tkr[r] = tk;
    }
    if (by == 0 && wu == 0 && lo16 == 0){
      #pragma unroll
      for (int r=0;r<4;r++){
        float* op = out + ((size_t)(r0+r)*TDEC + (t-1))*5;
        #pragma unroll
        for (int v=0;v<5;v++) op[v] = acc5[r][v];
      }
    }
  }

  #pragma unroll
  for (int r=0;r<4;r++){
    const int e = r0 + r;
    const float* ep = egen0 + (size_t)tkr[r]*2048 + u;
    float zi = aHH[0][r]+aLH[0][r]+aHL[0][r] + ep[0];
    float zf = aHH[1][r]+aLH[1][r]+aHL[1][r] + ep[512];
    float zg = aHH[2][r]+aLH[2][r]+aHL[2][r] + ep[1024];
    float zo = aHH[3][r]+aLH[3][r]+aHL[3][r] + ep[1536];
    const size_t idx = (size_t)e*512 + u;
    float c = sigf(zf)*cst[idx] + sigf(zi)*tanhf(zg);
    float h = sigf(zo)*tanhf(c);
    cst[idx] = c;
    unsigned short hb = f2bf(h);
    hoh[idx] = hb;
    hol[idx] = f2bf(h - bf2f(hb));
  }
}

// ------------- decoder layer 1 (staged MFMA, pure LSTM) --------------------- (R9)
__global__ void __launch_bounds__(512,1) dec_l1_mfma(
    const unsigned short* __restrict__ xh, const unsigned short* __restrict__ xl,
    const unsigned short* __restrict__ wh, const unsigned short* __restrict__ wl,
    const float* __restrict__ bias,
    const unsigned short* __restrict__ hih, const unsigned short* __restrict__ hil,
    unsigned short* __restrict__ hoh, unsigned short* __restrict__ hol,
    float* __restrict__ cst)
{
  __shared__ unsigned short bsm[2][32768];
  const int bid = blockIdx.x;
  const int by = bid & 15;
  const int bx = bid >> 4;
  const int e0 = bx * 64;
  const int lane = threadIdx.x & 63;
  const int w = threadIdx.x >> 6;
  const int wm = w & 3, wu = w >> 2;
  const int ut = by*2 + wu;
  const int lo16 = lane & 15, kgrp = lane >> 4;
  const int arow = e0 + wm*16 + lo16;
  const int u = ut*16 + lo16;
  const int r0 = e0 + wm*16 + kgrp*4;

  const unsigned short* pxh = xh  + (size_t)arow*512 + kgrp*8;
  const unsigned short* pxl = xl  + (size_t)arow*512 + kgrp*8;
  const unsigned short* pah = hih + (size_t)arow*512 + kgrp*8;
  const unsigned short* pal = hil + (size_t)arow*512 + kgrp*8;

  auto STAGE = [&](int c){
    #pragma unroll
    for (int i=0;i<8;i++){
      int id = w*8 + i;
      int hl  = id & 1;
      int q   = (id >> 1) & 3;
      int wu2 = (id >> 3) & 1;
      int ksl = id >> 4;
      int ks  = c*4 + ksl;
      const unsigned short* src = (hl ? wl : wh)
          + (((size_t)(q*32 + by*2 + wu2)*32 + ks)*64 + lane)*8;
      __builtin_amdgcn_global_load_lds((const void*)src,
          (void*)(&bsm[c & 1][id*512]), 16, 0, 0);
    }
  };

  const f32x4 z4 = {0.f,0.f,0.f,0.f};
  f32x4 aHH[4]={z4,z4,z4,z4}, aLH[4]={z4,z4,z4,z4}, aHL[4]={z4,z4,z4,z4};

  STAGE(0);
  __syncthreads();
  for (int c=0; c<8; c++){
    if (c+1 < 8) STAGE(c+1);
    const unsigned short* bb = &bsm[c&1][0];
    const unsigned short* pAh = (c < 4) ? pxh : pah;
    const unsigned short* pAl = (c < 4) ? pxl : pal;
    const int ksA = (c & 3)*4;
    #pragma unroll
    for (int ksl=0; ksl<4; ksl++){
      bf16x8 ah = *(const bf16x8*)(pAh + (size_t)(ksA+ksl)*32);
      bf16x8 al = *(const bf16x8*)(pAl + (size_t)(ksA+ksl)*32);
      #pragma unroll
      for (int q=0;q<4;q++){
        int fid = ((ksl*2 + wu)*4 + q)*2;
        bf16x8 bh = *(const bf16x8*)(bb + fid*512     + lane*8);
        bf16x8 bl = *(const bf16x8*)(bb + fid*512+512 + lane*8);
        aHH[q] = __builtin_amdgcn_mfma_f32_16x16x32_bf16(ah, bh, aHH[q], 0,0,0);
        aLH[q] = __builtin_amdgcn_mfma_f32_16x16x32_bf16(al, bh, aLH[q], 0,0,0);
        aHL[q] = __builtin_amdgcn_mfma_f32_16x16x32_bf16(ah, bl, aHL[q], 0,0,0);
      }
    }
    __syncthreads();
  }

  const float b0 = bias[u], b1 = bias[512+u], b2 = bias[1024+u], b3 = bias[1536+u];
  #pragma unroll
  for (int r=0;r<4;r++){
    const int e = r0 + r;
    float zi = aHH[0][r]+aLH[0][r]+aHL[0][r] + b0;
    float zf = aHH[1][r]+aLH[1][r]+aHL[1][r] + b1;
    float zg = aHH[2][r]+aLH[2][r]+aHL[2][r] + b2;
    float zo = aHH[3][r]+aLH[3][r]+aHL[3][r] + b3;
    const size_t idx = (size_t)e*512 + u;
    float c = sigf(zf)*cst[idx] + sigf(zi)*tanhf(zg);
    float h = sigf(zo)*tanhf(c);
    cst[idx] = c;
    unsigned short hb = f2bf(h);
    hoh[idx] = hb;
    hol[idx] = f2bf(h - bf2f(hb));
  }
}

// final-step logits (t = TDEC-1): one wave per batch elem
__global__ void dec_outF(const unsigned short* __restrict__ h1h,
                         const unsigned short* __restrict__ h1l,
                         const float* __restrict__ outW,
                         const float* __restrict__ outb,
                         float* __restrict__ out){
  const int lane = threadIdx.x & 63;
  const int e = blockIdx.x*4 + (threadIdx.x >> 6);
  const unsigned short* hh = h1h + (size_t)e*512;
  const unsigned short* hl = h1l + (size_t)e*512;
  float s0=0,s1=0,s2=0,s3=0,s4=0;
  for (int k=lane;k<512;k+=64){
    float hv = bf2f(hh[k]) + bf2f(hl[k]);
    s0 += hv*outW[k];
    s1 += hv*outW[512+k];
    s2 += hv*outW[1024+k];
    s3 += hv*outW[1536+k];
    s4 += hv*outW[2048+k];
  }
  #pragma unroll
  for (int off=32; off>0; off>>=1){
    s0 += __shfl_down(s0, off);
    s1 += __shfl_down(s1, off);
    s2 += __shfl_down(s2, off);
    s3 += __shfl_down(s3, off);
    s4 += __shfl_down(s4, off);
  }
  if (lane==0){
    float* op = out + ((size_t)e*TDEC + (TDEC-1))*5;
    op[0]=s0+outb[0]; op[1]=s1+outb[1]; op[2]=s2+outb[2];
    op[3]=s3+outb[3]; op[4]=s4+outb[4];
  }
}

extern "C" void kernel_launch(void* const* d_in, const int* in_sizes, int n_in,
                              void* d_out, int out_size, void* d_ws, size_t ws_size,
                              hipStream_t stream){
  (void)in_sizes; (void)n_in; (void)out_size;
  const int*   leftc    = (const int*)d_in[0];
  const int*   rightc   = (const int*)d_in[1];
  const float* emb      = (const float*)d_in[3];
  const float* ctx0_Wih = (const float*)d_in[4];
  const float* ctx0_Whh = (const float*)d_in[5];
  const float* ctx0_b   = (const float*)d_in[6];
  const float* ctx1_Wih = (const float*)d_in[7];
  const float* ctx1_Whh = (const float*)d_in[8];
  const float* ctx1_b   = (const float*)d_in[9];
  const float* gen0_Wih = (const float*)d_in[10];
  const float* gen0_Whh = (const float*)d_in[11];
  const float* gen0_b   = (const float*)d_in[12];
  const float* gen1_Wih = (const float*)d_in[13];
  const float* gen1_Whh = (const float*)d_in[14];
  const float* gen1_b   = (const float*)d_in[15];
  const float* out_W    = (const float*)d_in[16];
  const float* out_b    = (const float*)d_in[17];
  float* out = (float*)d_out;

  char* p = (char*)d_ws;
  auto carve = [&](size_t nfloats)->float*{
    float* r = (float*)p;
    p += ((nfloats*sizeof(float) + 255) & ~(size_t)255);
    return r;
  };
  auto carveu = [&](size_t nush)->unsigned short*{
    return (unsigned short*)carve((nush + 1)/2);
  };
  float* ectx0  = carve(2*5*1024);
  float* egen0  = carve(5*2048);
  float* leftF  = carve((size_t)BATCH*HG);
  float* rightF = carve((size_t)BATCH*HG);
  float* c0s    = carve((size_t)BATCH*HG);
  float* c1s    = carve((size_t)BATCH*HG);
  unsigned short* c0pkh = carveu((size_t)2*1024*256);
  unsigned short* c0pkl = carveu((size_t)2*1024*256);
  unsigned short* c1pkh = carveu((size_t)2*1024*768);
  unsigned short* c1pkl = carveu((size_t)2*1024*768);
  unsigned short* pk0h = carveu((size_t)2048*512);
  unsigned short* pk0l = carveu((size_t)2048*512);
  unsigned short* pk1h = carveu((size_t)2048*1024);
  unsigned short* pk1l = carveu((size_t)2048*1024);
  unsigned short* h0ha = carveu((size_t)BATCH*HG);
  unsigned short* h0la = carveu((size_t)BATCH*HG);
  unsigned short* h0hb = carveu((size_t)BATCH*HG);
  unsigned short* h0lb = carveu((size_t)BATCH*HG);
  unsigned short* h1ha = carveu((size_t)BATCH*HG);
  unsigned short* h1la = carveu((size_t)BATCH*HG);
  unsigned short* h1hb = carveu((size_t)BATCH*HG);
  unsigned short* h1lb = carveu((size_t)BATCH*HG);
  const size_t y0n = (size_t)L_SEQ*BATCH*512;
  unsigned short* y0Lh = carveu(y0n);   // 105 MB
  unsigned short* y0Ll = carveu(y0n);   // 105 MB
  if ((size_t)(p - (char*)d_ws) > ws_size) return;  // insufficient workspace -> loud fail

  // second y0 (right side) only if workspace allows -> merged ctx path
  unsigned short* y0Rh = nullptr;
  unsigned short* y0Rl = nullptr;
  {
    size_t used = (size_t)(p - (char*)d_ws);
    size_t need = 2 * (((y0n*sizeof(unsigned short) + 255) & ~(size_t)255));
    if (used + need <= ws_size){
      y0Rh = carveu(y0n);
      y0Rl = carveu(y0n);
    }
  }
  const bool merged = (y0Rh != nullptr);

  // weight packs (fragment-linear bf16 hi/lo)
  for (int d=0; d<2; d++){
    pack_w<<<128, 256, 0, stream>>>(ctx0_Whh + (size_t)d*1024*256, 1024, 256, 8, 0,
                                    c0pkh + (size_t)d*262144, c0pkl + (size_t)d*262144);
    pack_w<<<256, 256, 0, stream>>>(ctx1_Wih + (size_t)d*1024*512, 1024, 512, 24, 0,
                                    c1pkh + (size_t)d*786432, c1pkl + (size_t)d*786432);
    pack_w<<<128, 256, 0, stream>>>(ctx1_Whh + (size_t)d*1024*256, 1024, 256, 24, 16,
                                    c1pkh + (size_t)d*786432, c1pkl + (size_t)d*786432);
  }
  pack_w<<<512, 256, 0, stream>>>(gen0_Whh, 2048, 512, 16,  0, pk0h, pk0l);
  pack_w<<<512, 256, 0, stream>>>(gen1_Wih, 2048, 512, 32,  0, pk1h, pk1l);
  pack_w<<<512, 256, 0, stream>>>(gen1_Whh, 2048, 512, 32, 16, pk1h, pk1l);

  embprep<<<(20480+255)/256, 256, 0, stream>>>(emb, ctx0_Wih, ctx0_b,
                                               gen0_Wih, gen0_b, ectx0, egen0);

  if (merged){
    // both sides in one 256-block launch per layer (full GPU)
    ctx_l0_mfma<<<256, 512, 0, stream>>>(leftc, rightc, ectx0, c0pkh, c0pkl,
                                         y0Lh, y0Ll, y0Rh, y0Rl, -1);
    ctx_l1_mfma<<<256, 512, 0, stream>>>(y0Lh, y0Ll, y0Rh, y0Rl,
                                         c1pkh, c1pkl, ctx1_b, leftF, rightF, -1);
  } else {
    // sequential fallback: reuse y0L for both sides
    ctx_l0_mfma<<<128, 512, 0, stream>>>(leftc, rightc, ectx0, c0pkh, c0pkl,
                                         y0Lh, y0Ll, y0Lh, y0Ll, 0);
    ctx_l1_mfma<<<128, 512, 0, stream>>>(y0Lh, y0Ll, y0Lh, y0Ll,
                                         c1pkh, c1pkl, ctx1_b, leftF, rightF, 0);
    ctx_l0_mfma<<<128, 512, 0, stream>>>(leftc, rightc, ectx0, c0pkh, c0pkl,
                                         y0Lh, y0Ll, y0Lh, y0Ll, 1);
    ctx_l1_mfma<<<128, 512, 0, stream>>>(y0Lh, y0Ll, y0Lh, y0Ll,
                                         c1pkh, c1pkl, ctx1_b, leftF, rightF, 1);
  }

  combine_init2<<<(BATCH*HG+255)/256, 256, 0, stream>>>(leftF, rightF,
                                                        h0ha, h0la, h1ha, h1la,
                                                        c0s, c1s);

  for (int t=0;t<TDEC;t++){
    unsigned short* h0ih = (t&1)? h0hb : h0ha;
    unsigned short* h0il = (t&1)? h0lb : h0la;
    unsigned short* h0oh = (t&1)? h0ha : h0hb;
    unsigned short* h0ol = (t&1)? h0la : h0lb;
    unsigned short* h1ih = (t&1)? h1hb : h1ha;
    unsigned short* h1il = (t&1)? h1lb : h1la;
    unsigned short* h1oh = (t&1)? h1ha : h1hb;
    unsigned short* h1ol = (t&1)? h1la : h1lb;
    dec_l0_mfma<<<256, 512, 0, stream>>>(egen0, pk0h, pk0l,
                                         h0ih, h0il, h1ih, h1il,
                                         h0oh, h0ol, c0s,
                                         out_W, out_b, out, t);
    dec_l1_mfma<<<256, 512, 0, stream>>>(h0oh, h0ol, pk1h, pk1l, gen1_b,
                                         h1ih, h1il, h1oh, h1ol, c1s);
  }
  // t = TDEC-1 logits (h1 final lives in the 'a' buffers after odd t=255)
  dec_outF<<<256, 256, 0, stream>>>(h1ha, h1la, out_W, out_b, out);
}